// Round 14
// baseline (1270.869 us; speedup 1.0000x reference)
//
#include <hip/hip_runtime.h>
#include <hip/hip_bf16.h>

#define HIDDEN 3072
#define INTER  8192
#define NTOK   8192   // B*S = 4*2048

typedef __attribute__((ext_vector_type(8))) short bf16x8;
typedef __attribute__((ext_vector_type(4))) float f32x4;

__device__ __forceinline__ void gload_lds16(const void* g, void* l) {
  __builtin_amdgcn_global_load_lds(
      (const __attribute__((address_space(1))) void*)g,
      (__attribute__((address_space(3))) void*)l, 16, 0, 0);
}

__device__ __forceinline__ unsigned short f2bf(float f) {
  unsigned int u = __builtin_bit_cast(unsigned int, f);
  u += 0x7fffu + ((u >> 16) & 1u);   // round-to-nearest-even
  return (unsigned short)(u >> 16);
}

// ---------------- conversion kernels ----------------

__global__ void cvt_f32_bf16(const float* __restrict__ in,
                             unsigned short* __restrict__ out, int n4) {
  int i = blockIdx.x * blockDim.x + threadIdx.x;
  if (i >= n4) return;
  float4 v = reinterpret_cast<const float4*>(in)[i];
  ushort4 o;
  o.x = f2bf(v.x); o.y = f2bf(v.y); o.z = f2bf(v.z); o.w = f2bf(v.w);
  reinterpret_cast<ushort4*>(out)[i] = o;
}

__global__ void cvt_i32_bf16(const int* __restrict__ in,
                             unsigned short* __restrict__ out, int n4) {
  int i = blockIdx.x * blockDim.x + threadIdx.x;
  if (i >= n4) return;
  int4 v = reinterpret_cast<const int4*>(in)[i];
  ushort4 o;
  o.x = f2bf((float)v.x); o.y = f2bf((float)v.y);
  o.z = f2bf((float)v.z); o.w = f2bf((float)v.w);
  reinterpret_cast<ushort4*>(out)[i] = o;
}

// W_gu convert with gate/up row interleave at 16-row granularity:
// W'-row rowp = 32*(c>>4) + 16*u + (c&15), u=0 gate / 1 up.
__global__ void cvt_wgu_perm(const int* __restrict__ in,
                             unsigned short* __restrict__ out) {
  int i4 = blockIdx.x * blockDim.x + threadIdx.x;
  const int RW = HIDDEN / 4;   // 768 int4-groups per row
  if (i4 >= 2 * INTER * RW) return;
  int rowp = i4 / RW;
  int col4 = i4 - rowp * RW;
  int c = ((rowp >> 5) << 4) + (rowp & 15);
  int u = (rowp >> 4) & 1;
  int srow = u * INTER + c;
  int4 v = reinterpret_cast<const int4*>(in)[(size_t)srow * RW + col4];
  ushort4 o;
  o.x = f2bf((float)v.x); o.y = f2bf((float)v.y);
  o.z = f2bf((float)v.z); o.w = f2bf((float)v.w);
  reinterpret_cast<ushort4*>(out)[i4] = o;
}

// ------- 256x256 GEMM, 16x16x32 MFMA, m201-style locked phases -------
// Round-14 = R8's validated 8-barrier phase skeleton + ledger, PLUS the
// two instructions R8 was missing vs the m201 62%-MfmaUtil template:
//   after each phase's leading barrier:
//     asm("s_waitcnt lgkmcnt(0)")  -- raw s_barrier does NOT drain lgkm;
//       without this the compiler spreads lgkmcnt(N) micro-waits INSIDE
//       the 16-MFMA cluster (R8's 48.5%). The wait costs ~0 here because
//       barrier convergence already covered the ds_read latency.
//     __builtin_amdgcn_sched_barrier(0) -- rule #18: hipcc hoists
//       register-only MFMA past inline-asm lgkmcnt despite "memory".
// Phase p: {reads for THIS cluster; stage; [vmcnt]; BAR; lgkm0; SGB;
//           setprio1; 16 MFMA; setprio0; BAR}.
//
// Stage schedule + vmcnt ledger (VALIDATED R8/R9): per tile t:
//   P1 stage A(t+1)k0, P2 stage B(t+1)k0, P3 stage A(t+1)k1, P4 stage B(t+1)k1
//   entering t: 4 outstanding {A(t)k1,B(t)k1}; P2-end: 8 -> vmcnt(4) drains
//   t's kh1 (tail t=NT-1: vmcnt(0)); P4-end: vmcnt(4) drains (t+1)'s kh0.
// Swizzle (VALIDATED R6, 0 conflicts): cb ^= (row>>1)&3, involution both
// sides. NO unroll pragma on t-loop (R11: scratch spill, 2.7x regression).

template<int K, int N, int MODE>
__global__ __launch_bounds__(512, 2) void gemm8p(
    const unsigned short* __restrict__ A,   // [NTOK][K]
    const unsigned short* __restrict__ B,   // [N][K]
    const float* __restrict__ scale,
    void* __restrict__ outv)
{
  constexpr int NT = K / 64;
  __shared__ __align__(16) unsigned short lds[2][2][2][256 * 32];

  const int nbn = N / 256;
  const int nwg = (NTOK / 256) * nbn;       // %8 == 0 for both instantiations
  int bid = blockIdx.x;
  int wg = (bid & 7) * (nwg >> 3) + (bid >> 3);   // XCD-aware bijective swizzle
  const int bm = (wg / nbn) * 256;
  const int bn = (wg % nbn) * 256;

  const int tid  = threadIdx.x;
  const int lane = tid & 63;
  const int wid  = tid >> 6;
  const int wr = wid >> 2;                  // 0..1
  const int wc = wid & 3;                   // 0..3

  const int srow0 = tid >> 2;               // staging rows 0..127
  const int srow1 = 128 + (tid >> 2);       // staging rows 128..255
  const int scb   = tid & 3;

  const unsigned short* Ab = A + (size_t)bm * K;
  const unsigned short* Bb = B + (size_t)bn * K;

  auto stage = [&](const unsigned short* Gb, int op, int tt, int kh) {
    if (tt >= NT) return;
    int p = tt & 1;
    int kc = tt * 64 + kh * 32;
    unsigned short* lbase = &lds[p][op][kh][0];
    gload_lds16(Gb + (size_t)srow0 * K + kc + ((scb ^ ((srow0 >> 1) & 3)) * 8),
                lbase + (size_t)tid * 8);
    gload_lds16(Gb + (size_t)srow1 * K + kc + ((scb ^ ((srow1 >> 1) & 3)) * 8),
                lbase + (size_t)(512 + tid) * 8);
  };

  auto readA = [&](int p, int kh, int m) -> bf16x8 {
    int row = wr * 128 + m * 16 + (lane & 15);
    int cb = (lane >> 4) ^ ((row >> 1) & 3);
    return *(const bf16x8*)&lds[p][0][kh][row * 32 + cb * 8];
  };
  auto readB = [&](int p, int kh, int n) -> bf16x8 {
    int row = wc * 64 + n * 16 + (lane & 15);
    int cb = (lane >> 4) ^ ((row >> 1) & 3);
    return *(const bf16x8*)&lds[p][1][kh][row * 32 + cb * 8];
  };

  f32x4 acc[8][4] = {};
  bf16x8 aF[8], b0, b1;

  // prologue: stage tile 0's 4 half-tiles; drain kh0 (keep kh1 in flight)
  stage(Ab, 0, 0, 0);
  stage(Bb, 1, 0, 0);
  stage(Ab, 0, 0, 1);
  stage(Bb, 1, 0, 1);
  asm volatile("s_waitcnt vmcnt(4)" ::: "memory");
  __builtin_amdgcn_s_barrier();

  for (int t = 0; t < NT; ++t) {
    const int pr = t & 1;

    // ---- P1: reads kh0 (A m0-7, B n0-1); stage A(t+1)k0 ----
#pragma unroll
    for (int m = 0; m < 8; ++m) aF[m] = readA(pr, 0, m);
    b0 = readB(pr, 0, 0);
    b1 = readB(pr, 0, 1);
    stage(Ab, 0, t + 1, 0);
    __builtin_amdgcn_s_barrier();
    asm volatile("s_waitcnt lgkmcnt(0)" ::: "memory");
    __builtin_amdgcn_sched_barrier(0);
    __builtin_amdgcn_s_setprio(1);
#pragma unroll
    for (int m = 0; m < 8; ++m) {
      acc[m][0] = __builtin_amdgcn_mfma_f32_16x16x32_bf16(aF[m], b0, acc[m][0], 0, 0, 0);
      acc[m][1] = __builtin_amdgcn_mfma_f32_16x16x32_bf16(aF[m], b1, acc[m][1], 0, 0, 0);
    }
    __builtin_amdgcn_s_setprio(0);
    __builtin_amdgcn_s_barrier();

    // ---- P2: reads B n2-3 kh0; stage B(t+1)k0; W2 ----
    b0 = readB(pr, 0, 2);
    b1 = readB(pr, 0, 3);
    stage(Bb, 1, t + 1, 0);
    if (t + 1 < NT) {
      asm volatile("s_waitcnt vmcnt(4)" ::: "memory");
    } else {
      asm volatile("s_waitcnt vmcnt(0)" ::: "memory");
    }
    __builtin_amdgcn_s_barrier();
    asm volatile("s_waitcnt lgkmcnt(0)" ::: "memory");
    __builtin_amdgcn_sched_barrier(0);
    __builtin_amdgcn_s_setprio(1);
#pragma unroll
    for (int m = 0; m < 8; ++m) {
      acc[m][2] = __builtin_amdgcn_mfma_f32_16x16x32_bf16(aF[m], b0, acc[m][2], 0, 0, 0);
      acc[m][3] = __builtin_amdgcn_mfma_f32_16x16x32_bf16(aF[m], b1, acc[m][3], 0, 0, 0);
    }
    __builtin_amdgcn_s_setprio(0);
    __builtin_amdgcn_s_barrier();

    // ---- P3: reads kh1 (A m0-7, B n0-1); stage A(t+1)k1 ----
#pragma unroll
    for (int m = 0; m < 8; ++m) aF[m] = readA(pr, 1, m);
    b0 = readB(pr, 1, 0);
    b1 = readB(pr, 1, 1);
    stage(Ab, 0, t + 1, 1);
    __builtin_amdgcn_s_barrier();
    asm volatile("s_waitcnt lgkmcnt(0)" ::: "memory");
    __builtin_amdgcn_sched_barrier(0);
    __builtin_amdgcn_s_setprio(1);
#pragma unroll
    for (int m = 0; m < 8; ++m) {
      acc[m][0] = __builtin_amdgcn_mfma_f32_16x16x32_bf16(aF[m], b0, acc[m][0], 0, 0, 0);
      acc[m][1] = __builtin_amdgcn_mfma_f32_16x16x32_bf16(aF[m], b1, acc[m][1], 0, 0, 0);
    }
    __builtin_amdgcn_s_setprio(0);
    __builtin_amdgcn_s_barrier();

    // ---- P4: reads B n2-3 kh1; stage B(t+1)k1; W1 ----
    b0 = readB(pr, 1, 2);
    b1 = readB(pr, 1, 3);
    stage(Bb, 1, t + 1, 1);
    asm volatile("s_waitcnt vmcnt(4)" ::: "memory");   // no-op on last tile
    __builtin_amdgcn_s_barrier();
    asm volatile("s_waitcnt lgkmcnt(0)" ::: "memory");
    __builtin_amdgcn_sched_barrier(0);
    __builtin_amdgcn_s_setprio(1);
#pragma unroll
    for (int m = 0; m < 8; ++m) {
      acc[m][2] = __builtin_amdgcn_mfma_f32_16x16x32_bf16(aF[m], b0, acc[m][2], 0, 0, 0);
      acc[m][3] = __builtin_amdgcn_mfma_f32_16x16x32_bf16(aF[m], b1, acc[m][3], 0, 0, 0);
    }
    __builtin_amdgcn_s_setprio(0);
    __builtin_amdgcn_s_barrier();
  }

  // ---- epilogue: C/D layout col=lane&15, row=(lane>>4)*4+j ----
  const int crow0 = (lane >> 4) * 4;
  const int ccol  = lane & 15;
  if constexpr (MODE == 1) {
    // SwiGLU: n-frags (gate,up,gate,up) via 16-granular W interleave
    unsigned short* H = (unsigned short*)outv;     // [NTOK][INTER]
    const int hbase = (bn >> 1) + wc * 32;
#pragma unroll
    for (int np = 0; np < 2; ++np) {
      int hcol = hbase + np * 16 + ccol;
      float sg = scale[hcol];
      float su = scale[INTER + hcol];
#pragma unroll
      for (int m = 0; m < 8; ++m) {
#pragma unroll
        for (int j = 0; j < 4; ++j) {
          int row = bm + wr * 128 + m * 16 + crow0 + j;
          float g = acc[m][2 * np + 0][j] * sg;
          float u = acc[m][2 * np + 1][j] * su;
          float s = g / (1.0f + __expf(-g));       // silu
          H[(size_t)row * INTER + hcol] = f2bf(u * s);
        }
      }
    }
  } else {
    float* O = (float*)outv;                       // [NTOK][N]
#pragma unroll
    for (int n = 0; n < 4; ++n) {
      int col = bn + wc * 64 + n * 16 + ccol;
      float sc = scale[col];
#pragma unroll
      for (int m = 0; m < 8; ++m) {
#pragma unroll
        for (int j = 0; j < 4; ++j) {
          int row = bm + wr * 128 + m * 16 + crow0 + j;
          O[(size_t)row * N + col] = acc[m][n][j] * sc;
        }
      }
    }
  }
}

// ---------------- launch ----------------

extern "C" void kernel_launch(void* const* d_in, const int* in_sizes, int n_in,
                              void* d_out, int out_size, void* d_ws, size_t ws_size,
                              hipStream_t stream) {
  (void)in_sizes; (void)n_in; (void)out_size; (void)ws_size;

  const float* hidden = (const float*)d_in[0];   // [NTOK][HIDDEN] f32
  const int*   guq    = (const int*)d_in[1];     // [2*INTER][HIDDEN] i32
  const float* gus    = (const float*)d_in[2];   // [2*INTER]
  const int*   dwq    = (const int*)d_in[3];     // [HIDDEN][INTER] i32
  const float* dsc    = (const float*)d_in[4];   // [HIDDEN]
  float* out = (float*)d_out;

  char* ws = (char*)d_ws;
  unsigned short* xb  = (unsigned short*)(ws);                      // 50,331,648 B
  unsigned short* wgu = (unsigned short*)(ws + 50331648ull);        // 100,663,296 B (permuted)
  unsigned short* wd  = (unsigned short*)(ws + 150994944ull);       // 50,331,648 B
  unsigned short* hb  = (unsigned short*)(ws + 201326592ull);       // 134,217,728 B
  // total ws use: 335,544,320 B

  {
    int n4 = NTOK * HIDDEN / 4;
    cvt_f32_bf16<<<(n4 + 255) / 256, 256, 0, stream>>>(hidden, xb, n4);
  }
  {
    int n4 = 2 * INTER * HIDDEN / 4;
    cvt_wgu_perm<<<(n4 + 255) / 256, 256, 0, stream>>>(guq, wgu);
  }
  {
    int n4 = HIDDEN * INTER / 4;
    cvt_i32_bf16<<<(n4 + 255) / 256, 256, 0, stream>>>(dwq, wd, n4);
  }

  // GEMM1+SwiGLU: [8192 x 16384] over K=3072, writes H bf16 [8192][8192]
  gemm8p<HIDDEN, 2 * INTER, 1>
      <<<(NTOK / 256) * (2 * INTER / 256), 512, 0, stream>>>(xb, wgu, gus, hb);
  // GEMM2: [8192 x 3072] over K=8192, 256x256 tiles, f32 store
  gemm8p<INTER, HIDDEN, 2>
      <<<(NTOK / 256) * (HIDDEN / 256), 512, 0, stream>>>(hb, wd, dsc, out);
}

// Round 15
// 1238.349 us; speedup vs baseline: 1.0263x; 1.0263x over previous
//
#include <hip/hip_runtime.h>
#include <hip/hip_bf16.h>

#define HIDDEN 3072
#define INTER  8192
#define NTOK   8192   // B*S = 4*2048

typedef __attribute__((ext_vector_type(8))) short bf16x8;
typedef __attribute__((ext_vector_type(4))) float f32x4;

__device__ __forceinline__ void gload_lds16(const void* g, void* l) {
  __builtin_amdgcn_global_load_lds(
      (const __attribute__((address_space(1))) void*)g,
      (__attribute__((address_space(3))) void*)l, 16, 0, 0);
}

__device__ __forceinline__ unsigned short f2bf(float f) {
  unsigned int u = __builtin_bit_cast(unsigned int, f);
  u += 0x7fffu + ((u >> 16) & 1u);   // round-to-nearest-even
  return (unsigned short)(u >> 16);
}

// ---------------- conversion kernels ----------------

__global__ void cvt_f32_bf16(const float* __restrict__ in,
                             unsigned short* __restrict__ out, int n4) {
  int i = blockIdx.x * blockDim.x + threadIdx.x;
  if (i >= n4) return;
  float4 v = reinterpret_cast<const float4*>(in)[i];
  ushort4 o;
  o.x = f2bf(v.x); o.y = f2bf(v.y); o.z = f2bf(v.z); o.w = f2bf(v.w);
  reinterpret_cast<ushort4*>(out)[i] = o;
}

__global__ void cvt_i32_bf16(const int* __restrict__ in,
                             unsigned short* __restrict__ out, int n4) {
  int i = blockIdx.x * blockDim.x + threadIdx.x;
  if (i >= n4) return;
  int4 v = reinterpret_cast<const int4*>(in)[i];
  ushort4 o;
  o.x = f2bf((float)v.x); o.y = f2bf((float)v.y);
  o.z = f2bf((float)v.z); o.w = f2bf((float)v.w);
  reinterpret_cast<ushort4*>(out)[i] = o;
}

// W_gu convert with gate/up row interleave at 16-row granularity:
// W'-row rowp = 32*(c>>4) + 16*u + (c&15), u=0 gate / 1 up.
__global__ void cvt_wgu_perm(const int* __restrict__ in,
                             unsigned short* __restrict__ out) {
  int i4 = blockIdx.x * blockDim.x + threadIdx.x;
  const int RW = HIDDEN / 4;   // 768 int4-groups per row
  if (i4 >= 2 * INTER * RW) return;
  int rowp = i4 / RW;
  int col4 = i4 - rowp * RW;
  int c = ((rowp >> 5) << 4) + (rowp & 15);
  int u = (rowp >> 4) & 1;
  int srow = u * INTER + c;
  int4 v = reinterpret_cast<const int4*>(in)[(size_t)srow * RW + col4];
  ushort4 o;
  o.x = f2bf((float)v.x); o.y = f2bf((float)v.y);
  o.z = f2bf((float)v.z); o.w = f2bf((float)v.w);
  reinterpret_cast<ushort4*>(out)[i4] = o;
}

// ------- GEMM1: 256x256, 16x16x32 MFMA, phase-pipelined fragments -------
// BYTE-EXACT R10 structure (validated best: 1241us total, MfmaUtil 54.5,
// 0 conflicts). NO t-loop unroll pragma (R11: scratch spill). No lockstep
// lgkm-drain (R14: regressed). No stage-hoist (R13: neutral).
// See R10 comments for phase/ledger derivation.

template<int K, int N, int MODE>
__global__ __launch_bounds__(512, 2) void gemm8p(
    const unsigned short* __restrict__ A,   // [NTOK][K]
    const unsigned short* __restrict__ B,   // [N][K]
    const float* __restrict__ scale,
    void* __restrict__ outv)
{
  constexpr int NT = K / 64;
  __shared__ __align__(16) unsigned short lds[2][2][2][256 * 32];

  const int nbn = N / 256;
  const int nwg = (NTOK / 256) * nbn;
  int bid = blockIdx.x;
  int wg = (bid & 7) * (nwg >> 3) + (bid >> 3);   // XCD-aware bijective swizzle
  const int bm = (wg / nbn) * 256;
  const int bn = (wg % nbn) * 256;

  const int tid  = threadIdx.x;
  const int lane = tid & 63;
  const int wid  = tid >> 6;
  const int wr = wid >> 2;                  // 0..1
  const int wc = wid & 3;                   // 0..3

  const int srow0 = tid >> 2;               // staging rows 0..127
  const int srow1 = 128 + (tid >> 2);       // staging rows 128..255
  const int scb   = tid & 3;

  const unsigned short* Ab = A + (size_t)bm * K;
  const unsigned short* Bb = B + (size_t)bn * K;

  auto stage = [&](const unsigned short* Gb, int op, int tt, int kh) {
    if (tt >= NT) return;
    int p = tt & 1;
    int kc = tt * 64 + kh * 32;
    unsigned short* lbase = &lds[p][op][kh][0];
    gload_lds16(Gb + (size_t)srow0 * K + kc + ((scb ^ ((srow0 >> 1) & 3)) * 8),
                lbase + (size_t)tid * 8);
    gload_lds16(Gb + (size_t)srow1 * K + kc + ((scb ^ ((srow1 >> 1) & 3)) * 8),
                lbase + (size_t)(512 + tid) * 8);
  };

  auto readA = [&](int p, int kh, int m) -> bf16x8 {
    int row = wr * 128 + m * 16 + (lane & 15);
    int cb = (lane >> 4) ^ ((row >> 1) & 3);
    return *(const bf16x8*)&lds[p][0][kh][row * 32 + cb * 8];
  };
  auto readB = [&](int p, int kh, int n) -> bf16x8 {
    int row = wc * 64 + n * 16 + (lane & 15);
    int cb = (lane >> 4) ^ ((row >> 1) & 3);
    return *(const bf16x8*)&lds[p][1][kh][row * 32 + cb * 8];
  };

  f32x4 acc[8][4] = {};
  bf16x8 aP[4], aQ[4], bP[4], bQ[4];

  // prologue: stage tile 0 (4 half-tiles); drain k0; preload aP/bP
  stage(Ab, 0, 0, 0);
  stage(Bb, 1, 0, 0);
  stage(Ab, 0, 0, 1);
  stage(Bb, 1, 0, 1);
  asm volatile("s_waitcnt vmcnt(4)" ::: "memory");
  __builtin_amdgcn_s_barrier();
#pragma unroll
  for (int m = 0; m < 4; ++m) aP[m] = readA(0, 0, m);
#pragma unroll
  for (int n = 0; n < 4; ++n) bP[n] = readB(0, 0, n);

  for (int t = 0; t < NT; ++t) {
    const int pr = t & 1;

    // ---- Ph0: MFMA k0/h0 (aP x bP); read A(t,k0,h1)->aQ ----
#pragma unroll
    for (int m = 0; m < 4; ++m) aQ[m] = readA(pr, 0, m + 4);
    stage(Ab, 0, t + 1, 0);
    __builtin_amdgcn_s_setprio(1);
#pragma unroll
    for (int m = 0; m < 4; ++m)
#pragma unroll
      for (int n = 0; n < 4; ++n)
        acc[m][n] = __builtin_amdgcn_mfma_f32_16x16x32_bf16(aP[m], bP[n], acc[m][n], 0, 0, 0);
    __builtin_amdgcn_s_setprio(0);

    // ---- Ph1: drain kh1(t); BAR; read A(t,k1,h0)->aP, B(t,k1)->bQ;
    //           MFMA k0/h1 (aQ x bP) ----
    if (t + 1 < NT) {
      asm volatile("s_waitcnt vmcnt(2)" ::: "memory");
    } else {
      asm volatile("s_waitcnt vmcnt(0)" ::: "memory");
    }
    __builtin_amdgcn_s_barrier();
#pragma unroll
    for (int m = 0; m < 4; ++m) aP[m] = readA(pr, 1, m);
#pragma unroll
    for (int n = 0; n < 4; ++n) bQ[n] = readB(pr, 1, n);
    stage(Bb, 1, t + 1, 0);
    __builtin_amdgcn_s_setprio(1);
#pragma unroll
    for (int m = 0; m < 4; ++m)
#pragma unroll
      for (int n = 0; n < 4; ++n)
        acc[m + 4][n] = __builtin_amdgcn_mfma_f32_16x16x32_bf16(aQ[m], bP[n], acc[m + 4][n], 0, 0, 0);
    __builtin_amdgcn_s_setprio(0);

    // ---- Ph2: read A(t,k1,h1)->aQ; MFMA k1/h0 (aP x bQ); no barrier ----
#pragma unroll
    for (int m = 0; m < 4; ++m) aQ[m] = readA(pr, 1, m + 4);
    stage(Ab, 0, t + 1, 1);
    __builtin_amdgcn_s_setprio(1);
#pragma unroll
    for (int m = 0; m < 4; ++m)
#pragma unroll
      for (int n = 0; n < 4; ++n)
        acc[m][n] = __builtin_amdgcn_mfma_f32_16x16x32_bf16(aP[m], bQ[n], acc[m][n], 0, 0, 0);
    __builtin_amdgcn_s_setprio(0);

    // ---- Ph3: drain k0(t+1); BAR; read A(t+1,k0,h0)->aP, B(t+1,k0)->bP;
    //           MFMA k1/h1 (aQ x bQ) ----
    asm volatile("s_waitcnt vmcnt(2)" ::: "memory");
    __builtin_amdgcn_s_barrier();
    if (t + 1 < NT) {
#pragma unroll
      for (int m = 0; m < 4; ++m) aP[m] = readA(pr ^ 1, 0, m);
#pragma unroll
      for (int n = 0; n < 4; ++n) bP[n] = readB(pr ^ 1, 0, n);
    }
    stage(Bb, 1, t + 1, 1);
    __builtin_amdgcn_s_setprio(1);
#pragma unroll
    for (int m = 0; m < 4; ++m)
#pragma unroll
      for (int n = 0; n < 4; ++n)
        acc[m + 4][n] = __builtin_amdgcn_mfma_f32_16x16x32_bf16(aQ[m], bQ[n], acc[m + 4][n], 0, 0, 0);
    __builtin_amdgcn_s_setprio(0);
  }

  // ---- epilogue: C/D layout col=lane&15, row=(lane>>4)*4+j ----
  const int crow0 = (lane >> 4) * 4;
  const int ccol  = lane & 15;
  if constexpr (MODE == 1) {
    // SwiGLU: n-frags (gate,up,gate,up) via 16-granular W interleave
    unsigned short* H = (unsigned short*)outv;     // [NTOK][INTER]
    const int hbase = (bn >> 1) + wc * 32;
#pragma unroll
    for (int np = 0; np < 2; ++np) {
      int hcol = hbase + np * 16 + ccol;
      float sg = scale[hcol];
      float su = scale[INTER + hcol];
#pragma unroll
      for (int m = 0; m < 8; ++m) {
#pragma unroll
        for (int j = 0; j < 4; ++j) {
          int row = bm + wr * 128 + m * 16 + crow0 + j;
          float g = acc[m][2 * np + 0][j] * sg;
          float u = acc[m][2 * np + 1][j] * su;
          float s = g / (1.0f + __expf(-g));       // silu
          H[(size_t)row * INTER + hcol] = f2bf(u * s);
        }
      }
    }
  } else {
    float* O = (float*)outv;                       // [NTOK][N]
#pragma unroll
    for (int n = 0; n < 4; ++n) {
      int col = bn + wc * 64 + n * 16 + ccol;
      float sc = scale[col];
#pragma unroll
      for (int m = 0; m < 8; ++m) {
#pragma unroll
        for (int j = 0; j < 4; ++j) {
          int row = bm + wr * 128 + m * 16 + crow0 + j;
          O[(size_t)row * N + col] = acc[m][n][j] * sc;
        }
      }
    }
  }
}

// ------- GEMM2: 256x192 tile, grid 512 = EXACTLY 2 full CU-rounds -------
// Round-15: fixes the 384-block imbalance (2 rounds, 2nd half-empty) with
// tile geometry carrying ZERO staging/ledger change: B's LDS buffer stays
// 256 rows (rows 192-255 = pad, loaded with garbage from defined ws memory,
// never read) so staging is byte-identical to R10's proven 2-loads/stage
// schedule and vmcnt ledger. Per wave: 128x48 out = acc[8][3] (96 regs).
// R10 ping-pong phases with 3 n-frags (12-MFMA clusters).
// Swizzle: validated R6 family (0 conflicts; read rows 0..191 subset).

__global__ __launch_bounds__(512, 2) void gemm2_192(
    const unsigned short* __restrict__ A,   // [NTOK][INTER] (hb)
    const unsigned short* __restrict__ B,   // [HIDDEN][INTER] (wd)
    const float* __restrict__ scale,        // [HIDDEN]
    float* __restrict__ O)                  // [NTOK][HIDDEN]
{
  constexpr int K = INTER;
  constexpr int NT = K / 64;                // 128
  __shared__ __align__(16) unsigned short lds[2][2][2][256 * 32];

  const int nbn = HIDDEN / 192;             // 16
  const int nwg = (NTOK / 256) * nbn;       // 512 (%8==0)
  int bid = blockIdx.x;
  int wg = (bid & 7) * (nwg >> 3) + (bid >> 3);
  const int bm = (wg / nbn) * 256;
  const int bn = (wg % nbn) * 192;

  const int tid  = threadIdx.x;
  const int lane = tid & 63;
  const int wid  = tid >> 6;
  const int wr = wid >> 2;                  // 0..1 -> m-offset wr*128
  const int wc = wid & 3;                   // 0..3 -> n-offset wc*48

  const int srow0 = tid >> 2;               // staging rows 0..127
  const int srow1 = 128 + (tid >> 2);       // staging rows 128..255
  const int scb   = tid & 3;

  const unsigned short* Ab = A + (size_t)bm * K;
  const unsigned short* Bb = B + (size_t)bn * K;   // rows 192..255 = OOB-read pad (defined ws mem)

  auto stage = [&](const unsigned short* Gb, int op, int tt, int kh) {
    if (tt >= NT) return;
    int p = tt & 1;
    int kc = tt * 64 + kh * 32;
    unsigned short* lbase = &lds[p][op][kh][0];
    gload_lds16(Gb + (size_t)srow0 * K + kc + ((scb ^ ((srow0 >> 1) & 3)) * 8),
                lbase + (size_t)tid * 8);
    gload_lds16(Gb + (size_t)srow1 * K + kc + ((scb ^ ((srow1 >> 1) & 3)) * 8),
                lbase + (size_t)(512 + tid) * 8);
  };

  auto readA = [&](int p, int kh, int m) -> bf16x8 {
    int row = wr * 128 + m * 16 + (lane & 15);
    int cb = (lane >> 4) ^ ((row >> 1) & 3);
    return *(const bf16x8*)&lds[p][0][kh][row * 32 + cb * 8];
  };
  auto readB = [&](int p, int kh, int n) -> bf16x8 {
    int row = wc * 48 + n * 16 + (lane & 15);     // rows 0..191 only
    int cb = (lane >> 4) ^ ((row >> 1) & 3);
    return *(const bf16x8*)&lds[p][1][kh][row * 32 + cb * 8];
  };

  f32x4 acc[8][3] = {};
  bf16x8 aP[4], aQ[4], bP[3], bQ[3];

  // prologue: stage tile 0 (4 half-tiles); drain k0; preload aP/bP
  stage(Ab, 0, 0, 0);
  stage(Bb, 1, 0, 0);
  stage(Ab, 0, 0, 1);
  stage(Bb, 1, 0, 1);
  asm volatile("s_waitcnt vmcnt(4)" ::: "memory");
  __builtin_amdgcn_s_barrier();
#pragma unroll
  for (int m = 0; m < 4; ++m) aP[m] = readA(0, 0, m);
#pragma unroll
  for (int n = 0; n < 3; ++n) bP[n] = readB(0, 0, n);

  for (int t = 0; t < NT; ++t) {
    const int pr = t & 1;

    // ---- Ph0: MFMA k0/h0 (aP x bP); read A(t,k0,h1)->aQ ----
#pragma unroll
    for (int m = 0; m < 4; ++m) aQ[m] = readA(pr, 0, m + 4);
    stage(Ab, 0, t + 1, 0);
    __builtin_amdgcn_s_setprio(1);
#pragma unroll
    for (int m = 0; m < 4; ++m)
#pragma unroll
      for (int n = 0; n < 3; ++n)
        acc[m][n] = __builtin_amdgcn_mfma_f32_16x16x32_bf16(aP[m], bP[n], acc[m][n], 0, 0, 0);
    __builtin_amdgcn_s_setprio(0);

    // ---- Ph1: drain kh1(t); BAR; read A(t,k1,h0)->aP, B(t,k1)->bQ;
    //           MFMA k0/h1 (aQ x bP) ----
    if (t + 1 < NT) {
      asm volatile("s_waitcnt vmcnt(2)" ::: "memory");
    } else {
      asm volatile("s_waitcnt vmcnt(0)" ::: "memory");
    }
    __builtin_amdgcn_s_barrier();
#pragma unroll
    for (int m = 0; m < 4; ++m) aP[m] = readA(pr, 1, m);
#pragma unroll
    for (int n = 0; n < 3; ++n) bQ[n] = readB(pr, 1, n);
    stage(Bb, 1, t + 1, 0);
    __builtin_amdgcn_s_setprio(1);
#pragma unroll
    for (int m = 0; m < 4; ++m)
#pragma unroll
      for (int n = 0; n < 3; ++n)
        acc[m + 4][n] = __builtin_amdgcn_mfma_f32_16x16x32_bf16(aQ[m], bP[n], acc[m + 4][n], 0, 0, 0);
    __builtin_amdgcn_s_setprio(0);

    // ---- Ph2: read A(t,k1,h1)->aQ; MFMA k1/h0 (aP x bQ); no barrier ----
#pragma unroll
    for (int m = 0; m < 4; ++m) aQ[m] = readA(pr, 1, m + 4);
    stage(Ab, 0, t + 1, 1);
    __builtin_amdgcn_s_setprio(1);
#pragma unroll
    for (int m = 0; m < 4; ++m)
#pragma unroll
      for (int n = 0; n < 3; ++n)
        acc[m][n] = __builtin_amdgcn_mfma_f32_16x16x32_bf16(aP[m], bQ[n], acc[m][n], 0, 0, 0);
    __builtin_amdgcn_s_setprio(0);

    // ---- Ph3: drain k0(t+1); BAR; read A(t+1,k0,h0)->aP, B(t+1,k0)->bP;
    //           MFMA k1/h1 (aQ x bQ) ----
    asm volatile("s_waitcnt vmcnt(2)" ::: "memory");
    __builtin_amdgcn_s_barrier();
    if (t + 1 < NT) {
#pragma unroll
      for (int m = 0; m < 4; ++m) aP[m] = readA(pr ^ 1, 0, m);
#pragma unroll
      for (int n = 0; n < 3; ++n) bP[n] = readB(pr ^ 1, 0, n);
    }
    stage(Bb, 1, t + 1, 1);
    __builtin_amdgcn_s_setprio(1);
#pragma unroll
    for (int m = 0; m < 4; ++m)
#pragma unroll
      for (int n = 0; n < 3; ++n)
        acc[m + 4][n] = __builtin_amdgcn_mfma_f32_16x16x32_bf16(aQ[m], bQ[n], acc[m + 4][n], 0, 0, 0);
    __builtin_amdgcn_s_setprio(0);
  }

  // ---- epilogue: C/D layout col=lane&15, row=(lane>>4)*4+j ----
  const int crow0 = (lane >> 4) * 4;
  const int ccol  = lane & 15;
#pragma unroll
  for (int n = 0; n < 3; ++n) {
    int col = bn + wc * 48 + n * 16 + ccol;
    float sc = scale[col];
#pragma unroll
    for (int m = 0; m < 8; ++m) {
#pragma unroll
      for (int j = 0; j < 4; ++j) {
        int row = bm + wr * 128 + m * 16 + crow0 + j;
        O[(size_t)row * HIDDEN + col] = acc[m][n][j] * sc;
      }
    }
  }
}

// ---------------- launch ----------------

extern "C" void kernel_launch(void* const* d_in, const int* in_sizes, int n_in,
                              void* d_out, int out_size, void* d_ws, size_t ws_size,
                              hipStream_t stream) {
  (void)in_sizes; (void)n_in; (void)out_size; (void)ws_size;

  const float* hidden = (const float*)d_in[0];   // [NTOK][HIDDEN] f32
  const int*   guq    = (const int*)d_in[1];     // [2*INTER][HIDDEN] i32
  const float* gus    = (const float*)d_in[2];   // [2*INTER]
  const int*   dwq    = (const int*)d_in[3];     // [HIDDEN][INTER] i32
  const float* dsc    = (const float*)d_in[4];   // [HIDDEN]
  float* out = (float*)d_out;

  char* ws = (char*)d_ws;
  unsigned short* xb  = (unsigned short*)(ws);                      // 50,331,648 B
  unsigned short* wgu = (unsigned short*)(ws + 50331648ull);        // 100,663,296 B (permuted)
  unsigned short* wd  = (unsigned short*)(ws + 150994944ull);       // 50,331,648 B
  unsigned short* hb  = (unsigned short*)(ws + 201326592ull);       // 134,217,728 B
  // total ws use: 335,544,320 B

  {
    int n4 = NTOK * HIDDEN / 4;
    cvt_f32_bf16<<<(n4 + 255) / 256, 256, 0, stream>>>(hidden, xb, n4);
  }
  {
    int n4 = 2 * INTER * HIDDEN / 4;
    cvt_wgu_perm<<<(n4 + 255) / 256, 256, 0, stream>>>(guq, wgu);
  }
  {
    int n4 = HIDDEN * INTER / 4;
    cvt_i32_bf16<<<(n4 + 255) / 256, 256, 0, stream>>>(dwq, wd, n4);
  }

  // GEMM1+SwiGLU: [8192 x 16384] over K=3072, writes H bf16 [8192][8192]
  gemm8p<HIDDEN, 2 * INTER, 1>
      <<<(NTOK / 256) * (2 * INTER / 256), 512, 0, stream>>>(xb, wgu, gus, hb);
  // GEMM2: [8192 x 3072] over K=8192, 256x192 tiles, grid 512 = 2 exact rounds
  gemm2_192<<<(NTOK / 256) * (HIDDEN / 192), 512, 0, stream>>>(hb, wd, dsc, out);
}